// Round 4
// baseline (251.268 us; speedup 1.0000x reference)
//
#include <hip/hip_runtime.h>

#define B_  2
#define T_  4096
#define D_  512
#define H_  8
#define HD_ 64
#define M_  (B_*T_)   // 8192 rows

typedef _Float16 h16;
typedef _Float16 v8h __attribute__((ext_vector_type(8)));
typedef _Float16 h2  __attribute__((ext_vector_type(2)));
typedef float v4f __attribute__((ext_vector_type(4)));
typedef unsigned short us;

#define AS1 __attribute__((address_space(1)))
#define AS3 __attribute__((address_space(3)))

__device__ __forceinline__ float bf2f(us u){
  union { unsigned int i; float f; } v; v.i = ((unsigned int)u) << 16; return v.f;
}
__device__ __forceinline__ us f2bf(float f){
  union { float f; unsigned int u; } v; v.f = f;
  unsigned int r = v.u + 0x7FFFu + ((v.u >> 16) & 1u);
  return (us)(r >> 16);
}
__device__ __forceinline__ v4f zero4(){ v4f z; z[0]=0.f; z[1]=0.f; z[2]=0.f; z[3]=0.f; return z; }

__device__ __forceinline__ void glds16(const h16* g, h16* l){
  __builtin_amdgcn_global_load_lds((const AS1 int*)(const void*)g,
                                   (AS3 int*)(void*)l, 16, 0, 0);
}

__device__ __forceinline__ h2 pkrtz(float a, float b){
  auto t = __builtin_amdgcn_cvt_pkrtz(a, b);   // v_cvt_pkrtz_f16_f32: {f16(a),f16(b)}
  h2 r; __builtin_memcpy(&r, &t, sizeof(r)); return r;
}

#define MFMA32 __builtin_amdgcn_mfma_f32_16x16x32_f16

// ---------------- fused convert: all inputs in ONE kernel -----------------------------
__global__ __launch_bounds__(256) void conv_all(
    const void* __restrict__ x, const void* __restrict__ w0, const void* __restrict__ w1,
    const void* __restrict__ w2, const void* __restrict__ w3, const void* __restrict__ bo,
    h16* __restrict__ xb, h16* __restrict__ d0, h16* __restrict__ d1,
    h16* __restrict__ d2, h16* __restrict__ d3, float* __restrict__ bof)
{
  const int bid = blockIdx.x, tid = threadIdx.x;
  const void* src; int o0; int seg;
  h16* dst = nullptr;
  if (bid < 16384)      { src = x; o0 = bid * 256; dst = xb; seg = 0; }
  else if (bid < 20480) {
    const int wsel = (bid - 16384) >> 10;
    src = (wsel == 0) ? w0 : (wsel == 1) ? w1 : (wsel == 2) ? w2 : w3;
    dst = (wsel == 0) ? d0 : (wsel == 1) ? d1 : (wsel == 2) ? d2 : d3;
    o0 = ((bid - 16384) & 1023) * 256; seg = 0;
  } else                { src = bo; o0 = (bid - 20480) * 256; seg = 1; }

  __shared__ int sflag;
  if (tid == 0) sflag = 0;
  __syncthreads();
  const float probe = bf2f(((const us*)src)[o0 + tid]);
  if (!(fabsf(probe) < 1e4f)) atomicAdd(&sflag, 1);
  __syncthreads();
  const int isf32 = (sflag != 0);
  const int i = o0 + tid;
  const float v = isf32 ? ((const float*)src)[i] : bf2f(((const us*)src)[i]);
  if (seg) bof[i] = v;
  else     dst[i] = (h16)v;
}

// ---------------- GEMM core: Y[M,512] = A[M,512]*W[512,512]^T, f16 MFMA, fp32 acc -----
__device__ __forceinline__ void stage4(const h16* __restrict__ A, const h16* __restrict__ W,
                                       int m0, int n0, int kk, h16* sA, h16* sB, int tid){
  const int colA = (tid & 3) << 3;
  const int rowT = tid >> 2;
#pragma unroll
  for (int rd = 0; rd < 2; rd++) {
    const int row = rd * 64 + rowT;
    const int f = rd * 2048 + tid * 8;
    glds16(A + (size_t)(m0 + row) * D_ + kk + colA, sA + f);
    glds16(W + (size_t)(n0 + row) * D_ + kk + colA, sB + f);
  }
}

__device__ __forceinline__ void gemm_core(const h16* __restrict__ A,
                                          const h16* __restrict__ W,
                                          int m0, int n0, h16* sA, h16* sB,
                                          v4f acc[4][4]) {
  const int tid = threadIdx.x;
  const int lane = tid & 63, wid = tid >> 6;
  const int r = lane & 15, q = lane >> 4;
#pragma unroll
  for (int i = 0; i < 4; i++)
#pragma unroll
    for (int j = 0; j < 4; j++) acc[i][j] = zero4();

  stage4(A, W, m0, n0, 0, sA, sB, tid);
#pragma unroll 1
  for (int kt = 0; kt < 16; kt++) {
    if (kt < 15) {
      const int nb = (kt + 1) & 1;
      stage4(A, W, m0, n0, (kt + 1) * 32, sA + nb * 4096, sB + nb * 4096, tid);
      asm volatile("s_waitcnt vmcnt(4)" ::: "memory");   // current tile's 4 landed
    } else {
      asm volatile("s_waitcnt vmcnt(0)" ::: "memory");
    }
    asm volatile("s_barrier" ::: "memory");
    const h16* pA = sA + (kt & 1) * 4096 + ((wid & 1) * 64 + r) * 32 + q * 8;
    const h16* pB = sB + (kt & 1) * 4096 + ((wid >> 1) * 64 + r) * 32 + q * 8;
    v8h a[4], b[4];
#pragma unroll
    for (int i = 0; i < 4; i++) a[i] = *(const v8h*)(pA + i * 512);
#pragma unroll
    for (int j = 0; j < 4; j++) b[j] = *(const v8h*)(pB + j * 512);
#pragma unroll
    for (int i = 0; i < 4; i++)
#pragma unroll
      for (int j = 0; j < 4; j++)
        acc[i][j] = MFMA32(a[i], b[j], acc[i][j], 0, 0, 0);
    asm volatile("s_barrier" ::: "memory");              // done reading cur buffers
  }
}

// z=0 -> Q (pre-scaled by 0.125*log2e for exp2 softmax); z=1 -> K
// z=2 -> VT[b,h,hd,t'] with t' = pi-permuted within each 64-wide t-tile (PV slot order
// pi(8q+j)=4q+(j&3)+16*(j>>2)) — the attn PV B-operand reads v8h linearly from VT'.
__global__ __launch_bounds__(256, 3) void gemm_qkv(
    const h16* __restrict__ X,
    const h16* __restrict__ Wq, const h16* __restrict__ Wk, const h16* __restrict__ Wv,
    h16* __restrict__ Qo, h16* __restrict__ Ko, h16* __restrict__ VTo)
{
  __shared__ h16 sA[2 * 4096], sB[2 * 4096];
  const h16* W = (blockIdx.z == 0) ? Wq : (blockIdx.z == 1 ? Wk : Wv);
  const int m0 = blockIdx.x * 128, n0 = blockIdx.y * 128;
  v4f acc[4][4];
  gemm_core(X, W, m0, n0, sA, sB, acc);
  const int lane = threadIdx.x & 63, wid = threadIdx.x >> 6;
  const int r = lane & 15, q = lane >> 4;
  const int wm = m0 + (wid & 1) * 64, wn = n0 + (wid >> 1) * 64;
  if (blockIdx.z == 2) {
#pragma unroll
    for (int i = 0; i < 4; i++)
#pragma unroll
      for (int j = 0; j < 4; j++)
#pragma unroll
        for (int rr = 0; rr < 4; rr++) {
          const int row = wm + i*16 + q*4 + rr;   // b*T + t
          const int col = wn + j*16 + r;          // h*64 + hd
          const int bb = row >> 12, tt = row & (T_ - 1);
          const int hh = col >> 6,  hd = col & 63;
          const int t6 = tt & 63;
          const int tperm = (tt & ~63) | (t6 & 3) | (((t6 >> 2) & 3) << 3)
                          | (((t6 >> 4) & 1) << 2) | (t6 & 32);
          VTo[((size_t)(((bb << 3) + hh) << 6) + hd) * T_ + tperm] = (h16)acc[i][j][rr];
        }
  } else {
    h16* Y = (blockIdx.z == 0) ? Qo : Ko;
    const float sc = (blockIdx.z == 0) ? 0.1803368801f : 1.0f;  // 1/8 * log2(e)
#pragma unroll
    for (int i = 0; i < 4; i++)
#pragma unroll
      for (int j = 0; j < 4; j++)
#pragma unroll
        for (int rr = 0; rr < 4; rr++)
          Y[(size_t)(wm + i*16 + q*4 + rr) * D_ + wn + j*16 + r] = (h16)(acc[i][j][rr] * sc);
  }
}

__global__ __launch_bounds__(256, 3) void gemm_out(
    const h16* __restrict__ A, const h16* __restrict__ W,
    const float* __restrict__ bias, void* __restrict__ out, const void* __restrict__ xprobe)
{
  __shared__ h16 sA[2 * 4096], sB[2 * 4096];
  __shared__ int sflag;
  if (threadIdx.x == 0) sflag = 0;
  __syncthreads();
  const float probe = bf2f(((const us*)xprobe)[threadIdx.x]);
  if (!(fabsf(probe) < 1e4f)) atomicAdd(&sflag, 1);
  __syncthreads();
  const int flag = (sflag != 0);

  const int m0 = blockIdx.x * 128, n0 = blockIdx.y * 128;
  v4f acc[4][4];
  gemm_core(A, W, m0, n0, sA, sB, acc);
  const int lane = threadIdx.x & 63, wid = threadIdx.x >> 6;
  const int r = lane & 15, q = lane >> 4;
  const int wm = m0 + (wid & 1) * 64, wn = n0 + (wid >> 1) * 64;
#pragma unroll
  for (int i = 0; i < 4; i++)
#pragma unroll
    for (int j = 0; j < 4; j++)
#pragma unroll
      for (int rr = 0; rr < 4; rr++) {
        const int row = wm + i*16 + q*4 + rr;
        const int col = wn + j*16 + r;
        const float v = acc[i][j][rr] + bias[col];
        if (flag) ((float*)out)[(size_t)row * D_ + col] = v;
        else ((us*)out)[(size_t)row * D_ + col] = f2bf(v);
      }
}

// ---------------- flash attention, ROUND 14: k-split waves, NO LDS main loop ---------
// Wave (kw=wid&1, qw=wid>>1) owns a 32-wide k-slice x 32-q half. The 4 waves' K/V
// slices are disjoint -> no cross-wave reuse -> LDS staging deleted entirely. Each
// wave streams K-slice + pi-permuted V^T-slice from L2 (head pinned to one XCD by
// grid x=head) straight into registers: 8 coalesced 16B-lane loads/tile, 0 LDS ops,
// 0 barriers in the main loop. K prefetched 1 tile ahead (A/B sets, even/odd unroll
// so all reg indices are compile-time); V issued at body start (covered by QK+exp2).
// P slot order (kf,rr) == pi order encoded in VT' (verified rounds 0-3) -> PV is
// mfma32(pa, va) directly. Per-block epilogue: kw=1 waves ship O (8KB f32) + l via
// LDS scratch, ONE __syncthreads, kw=0 waves add, normalize, store.
struct KFrag { v8h a0, a1, b0, b1; };   // [kf0|kf1] x [hd 0-31 | hd 32-63]
struct VFrag { v8h v[4]; };             // hd-blocks 0..3, this wave's 32-k pi-cols

__global__ __launch_bounds__(256, 3) void attn_kernel(
    const h16* __restrict__ Q, const h16* __restrict__ K,
    const h16* __restrict__ VT, h16* __restrict__ Ctx)
{
  const int h = blockIdx.x;
  const int pos = blockIdx.y + (blockIdx.z << 6);      // dispatch position 0..127
  const int qc = 63 - (pos >> 1);                      // strict LPT: heavy first
  const int b  = pos & 1;
  const int tid = threadIdx.x;
  const int wid = tid >> 6, lane = tid & 63;
  const int r = lane & 15, quad = lane >> 4;
  const int kw = wid & 1, qw = wid >> 1;

  const size_t headoff = (size_t)b * T_ * D_ + (size_t)h * HD_;
  const h16* Qh  = Q + headoff;
  const h16* Kh  = K + headoff;
  const h16* VTh = VT + (size_t)(b * H_ + h) * HD_ * T_;
  h16* Ch = Ctx + headoff;

  __shared__ float red[4288];   // 2 segs * (32 rows * 66) + 64 lred = 17152 B

  // Q fragments: 2 q-subtiles (qb) x 2 hd-halves, rows qc*64 + qw*32 + qb*16 + r
  const int q0 = qc * 64 + qw * 32 + r;
  const v8h aq00 = *(const v8h*)(Qh + (size_t)q0 * D_ + quad * 8);
  const v8h aq01 = *(const v8h*)(Qh + (size_t)q0 * D_ + 32 + quad * 8);
  const v8h aq10 = *(const v8h*)(Qh + (size_t)(q0 + 16) * D_ + quad * 8);
  const v8h aq11 = *(const v8h*)(Qh + (size_t)(q0 + 16) * D_ + 32 + quad * 8);

  v8h vone;
#pragma unroll
  for (int e = 0; e < 8; e++) vone[e] = (h16)1;

  v4f o0[4], o1[4];
#pragma unroll
  for (int j = 0; j < 4; j++) { o0[j] = zero4(); o1[j] = zero4(); }
  v4f ld0 = zero4(), ld1 = zero4();

  // streaming bases (lane-varying parts fixed; tile advance is uniform)
  const h16* kbase = Kh + (size_t)(kw * 32 + r) * D_ + quad * 8;
  const h16* vbase = VTh + (size_t)r * T_ + kw * 32 + quad * 8;
  const int kloc = kw * 32 + quad * 4;
  const int qlim0 = qw * 32 + r, qlim1 = qw * 32 + 16 + r;

#define ISSUEK(F, KT) do {                                                     \
    const h16* kp_ = kbase + (size_t)(KT) * (64 * D_);                         \
    F.a0 = *(const v8h*)(kp_);                                                 \
    F.a1 = *(const v8h*)(kp_ + 32);                                            \
    F.b0 = *(const v8h*)(kp_ + 16 * D_);                                       \
    F.b1 = *(const v8h*)(kp_ + 16 * D_ + 32);                                  \
  } while(0)

#define ISSUEV(V, KT) do {                                                     \
    const h16* vp_ = vbase + (size_t)(KT) * 64;                                \
    _Pragma("unroll")                                                          \
    for (int hdb_ = 0; hdb_ < 4; hdb_++)                                       \
      V.v[hdb_] = *(const v8h*)(vp_ + (size_t)hdb_ * 16 * T_);                 \
  } while(0)

#define PQB(SA, SB, QLIM, PAU, MASKED) do {                                    \
    float e_[8];                                                               \
    _Pragma("unroll")                                                          \
    for (int rr = 0; rr < 4; rr++) {                                           \
      float v0_ = SA[rr], v1_ = SB[rr];                                        \
      if (MASKED) {                                                            \
        if (kloc + rr > (QLIM)) v0_ = -1e30f;                                  \
        if (kloc + 16 + rr > (QLIM)) v1_ = -1e30f;                             \
      }                                                                        \
      e_[rr] = exp2f(v0_); e_[4 + rr] = exp2f(v1_);                            \
    }                                                                          \
    PAU.p[0] = pkrtz(e_[0], e_[1]); PAU.p[1] = pkrtz(e_[2], e_[3]);            \
    PAU.p[2] = pkrtz(e_[4], e_[5]); PAU.p[3] = pkrtz(e_[6], e_[7]);            \
  } while(0)

#define BODY(F, V, MASKED) do {                                                \
    v4f s00 = zero4(), s01 = zero4(), s10 = zero4(), s11 = zero4();            \
    s00 = MFMA32(F.a0, aq00, s00, 0,0,0); s00 = MFMA32(F.a1, aq01, s00, 0,0,0);\
    s01 = MFMA32(F.a0, aq10, s01, 0,0,0); s01 = MFMA32(F.a1, aq11, s01, 0,0,0);\
    s10 = MFMA32(F.b0, aq00, s10, 0,0,0); s10 = MFMA32(F.b1, aq01, s10, 0,0,0);\
    s11 = MFMA32(F.b0, aq10, s11, 0,0,0); s11 = MFMA32(F.b1, aq11, s11, 0,0,0);\
    union { v8h v; h2 p[4]; } pa0, pa1;                                        \
    PQB(s00, s10, qlim0, pa0, MASKED);                                         \
    PQB(s01, s11, qlim1, pa1, MASKED);                                         \
    ld0 = MFMA32(pa0.v, vone, ld0, 0,0,0);                                     \
    ld1 = MFMA32(pa1.v, vone, ld1, 0,0,0);                                     \
    _Pragma("unroll")                                                          \
    for (int hdb_ = 0; hdb_ < 4; hdb_++) {                                     \
      o0[hdb_] = MFMA32(pa0.v, V.v[hdb_], o0[hdb_], 0,0,0);                    \
      o1[hdb_] = MFMA32(pa1.v, V.v[hdb_], o1[hdb_], 0,0,0);                    \
    }                                                                          \
  } while(0)

  KFrag fA, fB;
  VFrag vx, vy;
  ISSUEK(fA, 0);
  const int nm = qc;                 // unmasked tiles; tile nm is the diagonal
  int kt = 0;
  while (kt + 2 <= nm) {
    ISSUEV(vx, kt);     ISSUEK(fB, kt + 1); BODY(fA, vx, false);
    ISSUEV(vy, kt + 1); ISSUEK(fA, kt + 2); BODY(fB, vy, false);
    kt += 2;
  }
  if (kt < nm) {                     // one unmasked left (in fA), diagonal in fB
    ISSUEV(vx, kt); ISSUEK(fB, kt + 1); BODY(fA, vx, false);
    ISSUEV(vy, nm); BODY(fB, vy, true);
  } else {                           // diagonal tile in fA
    ISSUEV(vx, nm); BODY(fA, vx, true);
  }

  // ---------------- epilogue: one-shot cross-wave (kw) reduction ----------------
  float* seg = red + qw * 2112;      // 32 rows x 66 f32
  float* lred = red + 4224;
  if (kw) {
#pragma unroll
    for (int hdb = 0; hdb < 4; hdb++)
#pragma unroll
      for (int j = 0; j < 4; j++) {
        seg[(quad * 4 + j) * 66 + hdb * 16 + r] = o0[hdb][j];
        seg[(16 + quad * 4 + j) * 66 + hdb * 16 + r] = o1[hdb][j];
      }
    if (r == 0) {
#pragma unroll
      for (int j = 0; j < 4; j++) {
        lred[qw * 32 + quad * 4 + j] = ld0[j];
        lred[qw * 32 + 16 + quad * 4 + j] = ld1[j];
      }
    }
  }
  __syncthreads();
  if (!kw) {
    float inv0[4], inv1[4];
#pragma unroll
    for (int j = 0; j < 4; j++) {
      inv0[j] = 1.0f / (ld0[j] + lred[qw * 32 + quad * 4 + j]);
      inv1[j] = 1.0f / (ld1[j] + lred[qw * 32 + 16 + quad * 4 + j]);
    }
#pragma unroll
    for (int hdb = 0; hdb < 4; hdb++)
#pragma unroll
      for (int j = 0; j < 4; j++) {
        const float a0 = o0[hdb][j] + seg[(quad * 4 + j) * 66 + hdb * 16 + r];
        const float a1 = o1[hdb][j] + seg[(16 + quad * 4 + j) * 66 + hdb * 16 + r];
        Ch[(size_t)(qc * 64 + qw * 32 + quad * 4 + j) * D_ + hdb * 16 + r] =
            (h16)(a0 * inv0[j]);
        Ch[(size_t)(qc * 64 + qw * 32 + 16 + quad * 4 + j) * D_ + hdb * 16 + r] =
            (h16)(a1 * inv1[j]);
      }
  }
#undef ISSUEK
#undef ISSUEV
#undef PQB
#undef BODY
}

// ---------------- launch ----------------
extern "C" void kernel_launch(void* const* d_in, const int* in_sizes, int n_in,
                              void* d_out, int out_size, void* d_ws, size_t ws_size,
                              hipStream_t stream) {
  char* ws = (char*)d_ws;
  h16* xb  = (h16*)(ws + 0);                   // 8 MiB X f16
  h16* qb  = (h16*)(ws + 8388608);             // 8 MiB Q (pre-scaled by 0.125*log2e)
  h16* kb  = (h16*)(ws + 16777216);            // 8 MiB K
  h16* vt  = (h16*)(ws + 25165824);            // 8 MiB V^T (pi-permuted cols)
  h16* ctx = (h16*)(ws + 33554432);            // 8 MiB attention output
  h16* wqb = (h16*)(ws + 41943040);            // 512 KiB each
  h16* wkb = (h16*)(ws + 41943040 + 524288);
  h16* wvb = (h16*)(ws + 41943040 + 2 * 524288);
  h16* wob = (h16*)(ws + 41943040 + 3 * 524288);
  float* bof = (float*)(ws + 41943040 + 4 * 524288);

  conv_all<<<20482, 256, 0, stream>>>(d_in[0], d_in[1], d_in[2], d_in[3], d_in[4],
                                      d_in[5], xb, wqb, wkb, wvb, wob, bof);
  gemm_qkv<<<dim3(M_ / 128, D_ / 128, 3), 256, 0, stream>>>(xb, wqb, wkb, wvb, qb, kb, vt);
  attn_kernel<<<dim3(H_, 64, B_), 256, 0, stream>>>(qb, kb, vt, ctx);
  gemm_out<<<dim3(M_ / 128, D_ / 128, 1), 256, 0, stream>>>(ctx, wob, bof, d_out, d_in[0]);
}

// Round 7
// 179.779 us; speedup vs baseline: 1.3976x; 1.3976x over previous
//
#include <hip/hip_runtime.h>

#define B_  2
#define T_  4096
#define D_  512
#define H_  8
#define HD_ 64
#define M_  (B_*T_)   // 8192 rows

typedef _Float16 h16;
typedef _Float16 v8h __attribute__((ext_vector_type(8)));
typedef _Float16 h2  __attribute__((ext_vector_type(2)));
typedef float v4f __attribute__((ext_vector_type(4)));
typedef unsigned short us;

union PaU { v8h v; h2 p[4]; };

#define AS1 __attribute__((address_space(1)))
#define AS3 __attribute__((address_space(3)))

__device__ __forceinline__ float bf2f(us u){
  union { unsigned int i; float f; } v; v.i = ((unsigned int)u) << 16; return v.f;
}
__device__ __forceinline__ us f2bf(float f){
  union { float f; unsigned int u; } v; v.f = f;
  unsigned int r = v.u + 0x7FFFu + ((v.u >> 16) & 1u);
  return (us)(r >> 16);
}
__device__ __forceinline__ v4f zero4(){ v4f z; z[0]=0.f; z[1]=0.f; z[2]=0.f; z[3]=0.f; return z; }

__device__ __forceinline__ void glds16(const h16* g, h16* l){
  __builtin_amdgcn_global_load_lds((const AS1 int*)(const void*)g,
                                   (AS3 int*)(void*)l, 16, 0, 0);
}

__device__ __forceinline__ h2 pkrtz(float a, float b){
  auto t = __builtin_amdgcn_cvt_pkrtz(a, b);   // v_cvt_pkrtz_f16_f32: {f16(a),f16(b)}
  h2 r; __builtin_memcpy(&r, &t, sizeof(r)); return r;
}

#define MFMA32 __builtin_amdgcn_mfma_f32_16x16x32_f16

// ---------------- fused convert: all inputs in ONE kernel -----------------------------
__global__ __launch_bounds__(256) void conv_all(
    const void* __restrict__ x, const void* __restrict__ w0, const void* __restrict__ w1,
    const void* __restrict__ w2, const void* __restrict__ w3, const void* __restrict__ bo,
    h16* __restrict__ xb, h16* __restrict__ d0, h16* __restrict__ d1,
    h16* __restrict__ d2, h16* __restrict__ d3, float* __restrict__ bof)
{
  const int bid = blockIdx.x, tid = threadIdx.x;
  const void* src; int o0; int seg;
  h16* dst = nullptr;
  if (bid < 16384)      { src = x; o0 = bid * 256; dst = xb; seg = 0; }
  else if (bid < 20480) {
    const int wsel = (bid - 16384) >> 10;
    src = (wsel == 0) ? w0 : (wsel == 1) ? w1 : (wsel == 2) ? w2 : w3;
    dst = (wsel == 0) ? d0 : (wsel == 1) ? d1 : (wsel == 2) ? d2 : d3;
    o0 = ((bid - 16384) & 1023) * 256; seg = 0;
  } else                { src = bo; o0 = (bid - 20480) * 256; seg = 1; }

  __shared__ int sflag;
  if (tid == 0) sflag = 0;
  __syncthreads();
  const float probe = bf2f(((const us*)src)[o0 + tid]);
  if (!(fabsf(probe) < 1e4f)) atomicAdd(&sflag, 1);
  __syncthreads();
  const int isf32 = (sflag != 0);
  const int i = o0 + tid;
  const float v = isf32 ? ((const float*)src)[i] : bf2f(((const us*)src)[i]);
  if (seg) bof[i] = v;
  else     dst[i] = (h16)v;
}

// ---------------- GEMM core: Y[M,512] = A[M,512]*W[512,512]^T, f16 MFMA, fp32 acc -----
__device__ __forceinline__ void stage4(const h16* __restrict__ A, const h16* __restrict__ W,
                                       int m0, int n0, int kk, h16* sA, h16* sB, int tid){
  const int colA = (tid & 3) << 3;
  const int rowT = tid >> 2;
#pragma unroll
  for (int rd = 0; rd < 2; rd++) {
    const int row = rd * 64 + rowT;
    const int f = rd * 2048 + tid * 8;
    glds16(A + (size_t)(m0 + row) * D_ + kk + colA, sA + f);
    glds16(W + (size_t)(n0 + row) * D_ + kk + colA, sB + f);
  }
}

__device__ __forceinline__ void gemm_core(const h16* __restrict__ A,
                                          const h16* __restrict__ W,
                                          int m0, int n0, h16* sA, h16* sB,
                                          v4f acc[4][4]) {
  const int tid = threadIdx.x;
  const int lane = tid & 63, wid = tid >> 6;
  const int r = lane & 15, q = lane >> 4;
#pragma unroll
  for (int i = 0; i < 4; i++)
#pragma unroll
    for (int j = 0; j < 4; j++) acc[i][j] = zero4();

  stage4(A, W, m0, n0, 0, sA, sB, tid);
#pragma unroll 1
  for (int kt = 0; kt < 16; kt++) {
    if (kt < 15) {
      const int nb = (kt + 1) & 1;
      stage4(A, W, m0, n0, (kt + 1) * 32, sA + nb * 4096, sB + nb * 4096, tid);
      asm volatile("s_waitcnt vmcnt(4)" ::: "memory");   // current tile's 4 landed
    } else {
      asm volatile("s_waitcnt vmcnt(0)" ::: "memory");
    }
    asm volatile("s_barrier" ::: "memory");
    const h16* pA = sA + (kt & 1) * 4096 + ((wid & 1) * 64 + r) * 32 + q * 8;
    const h16* pB = sB + (kt & 1) * 4096 + ((wid >> 1) * 64 + r) * 32 + q * 8;
    v8h a[4], b[4];
#pragma unroll
    for (int i = 0; i < 4; i++) a[i] = *(const v8h*)(pA + i * 512);
#pragma unroll
    for (int j = 0; j < 4; j++) b[j] = *(const v8h*)(pB + j * 512);
#pragma unroll
    for (int i = 0; i < 4; i++)
#pragma unroll
      for (int j = 0; j < 4; j++)
        acc[i][j] = MFMA32(a[i], b[j], acc[i][j], 0, 0, 0);
    asm volatile("s_barrier" ::: "memory");              // done reading cur buffers
  }
}

// z=0 -> Q (pre-scaled by 0.125*log2e for exp2 softmax); z=1 -> K
// z=2 -> VT[b,h,hd,t'] with t' = pi-permuted within each 64-wide t-tile (PV slot order
// pi(8q+j)=4q+(j&3)+16*(j>>2), applied per 32-half) — attn PV B reads v8h linearly.
__global__ __launch_bounds__(256, 3) void gemm_qkv(
    const h16* __restrict__ X,
    const h16* __restrict__ Wq, const h16* __restrict__ Wk, const h16* __restrict__ Wv,
    h16* __restrict__ Qo, h16* __restrict__ Ko, h16* __restrict__ VTo)
{
  __shared__ h16 sA[2 * 4096], sB[2 * 4096];
  const h16* W = (blockIdx.z == 0) ? Wq : (blockIdx.z == 1 ? Wk : Wv);
  const int m0 = blockIdx.x * 128, n0 = blockIdx.y * 128;
  v4f acc[4][4];
  gemm_core(X, W, m0, n0, sA, sB, acc);
  const int lane = threadIdx.x & 63, wid = threadIdx.x >> 6;
  const int r = lane & 15, q = lane >> 4;
  const int wm = m0 + (wid & 1) * 64, wn = n0 + (wid >> 1) * 64;
  if (blockIdx.z == 2) {
#pragma unroll
    for (int i = 0; i < 4; i++)
#pragma unroll
      for (int j = 0; j < 4; j++)
#pragma unroll
        for (int rr = 0; rr < 4; rr++) {
          const int row = wm + i*16 + q*4 + rr;   // b*T + t
          const int col = wn + j*16 + r;          // h*64 + hd
          const int bb = row >> 12, tt = row & (T_ - 1);
          const int hh = col >> 6,  hd = col & 63;
          const int t6 = tt & 63;
          const int tperm = (tt & ~63) | (t6 & 3) | (((t6 >> 2) & 3) << 3)
                          | (((t6 >> 4) & 1) << 2) | (t6 & 32);
          VTo[((size_t)(((bb << 3) + hh) << 6) + hd) * T_ + tperm] = (h16)acc[i][j][rr];
        }
  } else {
    h16* Y = (blockIdx.z == 0) ? Qo : Ko;
    const float sc = (blockIdx.z == 0) ? 0.1803368801f : 1.0f;  // 1/8 * log2(e)
#pragma unroll
    for (int i = 0; i < 4; i++)
#pragma unroll
      for (int j = 0; j < 4; j++)
#pragma unroll
        for (int rr = 0; rr < 4; rr++)
          Y[(size_t)(wm + i*16 + q*4 + rr) * D_ + wn + j*16 + r] = (h16)(acc[i][j][rr] * sc);
  }
}

__global__ __launch_bounds__(256, 3) void gemm_out(
    const h16* __restrict__ A, const h16* __restrict__ W,
    const float* __restrict__ bias, void* __restrict__ out, const void* __restrict__ xprobe)
{
  __shared__ h16 sA[2 * 4096], sB[2 * 4096];
  __shared__ int sflag;
  if (threadIdx.x == 0) sflag = 0;
  __syncthreads();
  const float probe = bf2f(((const us*)xprobe)[threadIdx.x]);
  if (!(fabsf(probe) < 1e4f)) atomicAdd(&sflag, 1);
  __syncthreads();
  const int flag = (sflag != 0);

  const int m0 = blockIdx.x * 128, n0 = blockIdx.y * 128;
  v4f acc[4][4];
  gemm_core(A, W, m0, n0, sA, sB, acc);
  const int lane = threadIdx.x & 63, wid = threadIdx.x >> 6;
  const int r = lane & 15, q = lane >> 4;
  const int wm = m0 + (wid & 1) * 64, wn = n0 + (wid >> 1) * 64;
#pragma unroll
  for (int i = 0; i < 4; i++)
#pragma unroll
    for (int j = 0; j < 4; j++)
#pragma unroll
      for (int rr = 0; rr < 4; rr++) {
        const int row = wm + i*16 + q*4 + rr;
        const int col = wn + j*16 + r;
        const float v = acc[i][j][rr] + bias[col];
        if (flag) ((float*)out)[(size_t)row * D_ + col] = v;
        else ((us*)out)[(size_t)row * D_ + col] = f2bf(v);
      }
}

// ---------------- flash attention, ROUND 15c: LDS staging + 2D wave split ------------
// Round-3 pipeline (glds16 double-buffer, vmcnt(4), raw barriers) + k-split waves:
// wave (kw=wid&1, qw=wid>>1) owns a 32-k half x 32-q half of the 64x64 tile. Each wave
// reads only its K rows (4 ds_read_b128) and V cols (4), vs 16 for the full tile,
// while serving 2x q-rows: LDS read traffic per block-tile halves (64->32 KB). pi-slot
// order is per-32-half, so wave kw reads V cols kw*32+quad*8 with the same XOR swizzle.
// Epilogue: one cross-kw O+l reduction per block via LDS scratch aliased over the dead
// K/V buffers -> LDS stays 32 KB, 4 blocks/CU. (15b's LDS-pointer arrays replaced with
// direct smem[] indexing — addrspacecast static init doesn't compile on gfx950.)
__global__ __launch_bounds__(256, 4) void attn_kernel(
    const h16* __restrict__ Q, const h16* __restrict__ K,
    const h16* __restrict__ VT, h16* __restrict__ Ctx)
{
  const int h = blockIdx.x;
  const int pos = blockIdx.y + (blockIdx.z << 6);      // dispatch position 0..127
  const int qc = 63 - (pos >> 1);                      // strict LPT: heavy first
  const int b  = pos & 1;
  const int tid = threadIdx.x;
  const int wid = tid >> 6, lane = tid & 63;
  const int r = lane & 15, quad = lane >> 4;
  const int kw = wid & 1, qw = wid >> 1;

  const size_t headoff = (size_t)b * T_ * D_ + (size_t)h * HD_;
  const h16* Qh  = Q + headoff;
  const h16* Kh  = K + headoff;
  const h16* VTh = VT + (size_t)(b * H_ + h) * HD_ * T_;
  h16* Ch = Ctx + headoff;

  __shared__ h16 smem[4][4096];    // [0],[1]=K dbuf; [2],[3]=V dbuf; epilogue aliases

  const int q0 = qc * 64 + qw * 32;
  const int ntiles = qc + 1;

  // Q fragments (B-operand of swapped QK^T): 2 q-subtiles x 2 hd-halves
  const v8h aq00 = *(const v8h*)(Qh + (size_t)(q0 + r) * D_ + quad * 8);
  const v8h aq01 = *(const v8h*)(Qh + (size_t)(q0 + r) * D_ + 32 + quad * 8);
  const v8h aq10 = *(const v8h*)(Qh + (size_t)(q0 + 16 + r) * D_ + quad * 8);
  const v8h aq11 = *(const v8h*)(Qh + (size_t)(q0 + 16 + r) * D_ + 32 + quad * 8);

  v8h vone;
#pragma unroll
  for (int e = 0; e < 8; e++) vone[e] = (h16)1;

  v4f o0[4], o1[4];
#pragma unroll
  for (int j = 0; j < 4; j++) { o0[j] = zero4(); o1[j] = zero4(); }
  v4f ld0 = zero4(), ld1 = zero4();

  // staging: running pointers, XOR-swizzled dest rows (round-3 pattern)
  const int srow = tid >> 3;                           // 0..31
  const int sj = (tid & 7) ^ (srow & 7);
  const h16* kcur = Kh + (size_t)srow * D_ + sj * 8;
  const h16* vcur = VTh + (size_t)srow * T_ + sj * 8;

  glds16(kcur, &smem[0][tid * 8]); glds16(kcur + 32 * D_, &smem[0][2048 + tid * 8]);
  glds16(vcur, &smem[2][tid * 8]); glds16(vcur + 32 * T_, &smem[2][2048 + tid * 8]);
  kcur += 64 * D_; vcur += 64;

  // hoisted lane constants
  const int xo0 = (quad ^ (r & 7)) * 8;                // K hd-half 0
  const int xo1 = ((quad + 4) ^ (r & 7)) * 8;          // K hd-half 1
  const int xov = ((quad + kw * 4) ^ (r & 7)) * 8;     // V cols kw*32 + quad*8
  const int krow = kw * 32 + r;                        // this wave's K LDS row base
  const int kloc = kw * 32 + quad * 4;                 // k offset of s-reg rr=0
  const int qlim0 = qw * 32 + r, qlim1 = qw * 32 + 16 + r;

#pragma unroll 1
  for (int kt = 0; kt < ntiles; kt++) {
    const int cb = kt & 1;
    const h16* sKc = smem[cb];
    const h16* sVc = smem[2 + cb];
    if (kt + 1 < ntiles) {
      const int nb = (kt + 1) & 1;
      glds16(kcur, &smem[nb][tid * 8]);
      glds16(kcur + 32 * D_, &smem[nb][2048 + tid * 8]);
      glds16(vcur, &smem[2 + nb][tid * 8]);
      glds16(vcur + 32 * T_, &smem[2 + nb][2048 + tid * 8]);
      kcur += 64 * D_; vcur += 64;
      asm volatile("s_waitcnt vmcnt(4)" ::: "memory");   // current tile's 4 landed
    } else {
      asm volatile("s_waitcnt vmcnt(0)" ::: "memory");
    }
    asm volatile("s_barrier" ::: "memory");

    // this wave's K rows (kw half): kf=0 rows krow, kf=1 rows krow+16
    const h16* bK = sKc + krow * 64;
    const v8h ka0 = *(const v8h*)(bK + xo0);
    const v8h ka1 = *(const v8h*)(bK + xo1);
    const v8h ka2 = *(const v8h*)(bK + 16 * 64 + xo0);
    const v8h ka3 = *(const v8h*)(bK + 16 * 64 + xo1);
    // this wave's V cols (kw half), 4 hd-blocks
    v8h va[4];
#pragma unroll
    for (int j = 0; j < 4; j++)
      va[j] = *(const v8h*)(sVc + (j * 16 + r) * 64 + xov);

    // swapped QK^T: s[kf][qb]; D row = k (kloc + kf*16 + rr), col = q
    v4f s00 = zero4(), s10 = zero4(), s01 = zero4(), s11 = zero4();
    s00 = MFMA32(ka0, aq00, s00, 0,0,0); s00 = MFMA32(ka1, aq01, s00, 0,0,0);
    s10 = MFMA32(ka2, aq00, s10, 0,0,0); s10 = MFMA32(ka3, aq01, s10, 0,0,0);
    s01 = MFMA32(ka0, aq10, s01, 0,0,0); s01 = MFMA32(ka1, aq11, s01, 0,0,0);
    s11 = MFMA32(ka2, aq10, s11, 0,0,0); s11 = MFMA32(ka3, aq11, s11, 0,0,0);

    const bool dg = (kt == ntiles - 1);   // diagonal tile
    PaU pa0, pa1;
#pragma unroll
    for (int qb = 0; qb < 2; qb++) {
      const v4f& sa = qb ? s01 : s00;
      const v4f& sb = qb ? s11 : s10;
      const int qlim = qb ? qlim1 : qlim0;
      float e0[4], e1[4];
#pragma unroll
      for (int rr = 0; rr < 4; rr++) {
        float v0 = sa[rr], v1 = sb[rr];
        if (dg) {
          if (kloc + rr > qlim)      v0 = -1e30f;
          if (kloc + 16 + rr > qlim) v1 = -1e30f;
        }
        e0[rr] = exp2f(v0); e1[rr] = exp2f(v1);
      }
      PaU* pa = qb ? &pa1 : &pa0;
      pa->p[0] = pkrtz(e0[0], e0[1]); pa->p[1] = pkrtz(e0[2], e0[3]);
      pa->p[2] = pkrtz(e1[0], e1[1]); pa->p[3] = pkrtz(e1[2], e1[3]);
    }
    ld0 = MFMA32(pa0.v, vone, ld0, 0,0,0);
    ld1 = MFMA32(pa1.v, vone, ld1, 0,0,0);
#pragma unroll
    for (int j = 0; j < 4; j++) {
      o0[j] = MFMA32(pa0.v, va[j], o0[j], 0,0,0);
      o1[j] = MFMA32(pa1.v, va[j], o1[j], 0,0,0);
    }
    asm volatile("s_barrier" ::: "memory");              // done reading cur buffers
  }

  // ---------------- epilogue: cross-kw reduction (aliases dead K/V buffers) ----------
  __syncthreads();                   // all waves done with LDS tiles
  float* const red = (float*)&smem[0][0];      // 4288 f32 = 17152 B
  float* const seg = red + qw * 2112;          // 32 rows x 66
  float* const lred = red + 4224;
  if (kw) {
#pragma unroll
    for (int hdb = 0; hdb < 4; hdb++)
#pragma unroll
      for (int j = 0; j < 4; j++) {
        seg[(quad * 4 + j) * 66 + hdb * 16 + r] = o0[hdb][j];
        seg[(16 + quad * 4 + j) * 66 + hdb * 16 + r] = o1[hdb][j];
      }
    if (r == 0) {
#pragma unroll
      for (int j = 0; j < 4; j++) {
        lred[qw * 32 + quad * 4 + j] = ld0[j];
        lred[qw * 32 + 16 + quad * 4 + j] = ld1[j];
      }
    }
  }
  __syncthreads();
  if (!kw) {
    float inv0[4], inv1[4];
#pragma unroll
    for (int j = 0; j < 4; j++) {
      inv0[j] = 1.0f / (ld0[j] + lred[qw * 32 + quad * 4 + j]);
      inv1[j] = 1.0f / (ld1[j] + lred[qw * 32 + 16 + quad * 4 + j]);
    }
#pragma unroll
    for (int hdb = 0; hdb < 4; hdb++)
#pragma unroll
      for (int j = 0; j < 4; j++) {
        const float a0 = o0[hdb][j] + seg[(quad * 4 + j) * 66 + hdb * 16 + r];
        const float a1 = o1[hdb][j] + seg[(16 + quad * 4 + j) * 66 + hdb * 16 + r];
        Ch[(size_t)(q0 + quad * 4 + j) * D_ + hdb * 16 + r] = (h16)(a0 * inv0[j]);
        Ch[(size_t)(q0 + 16 + quad * 4 + j) * D_ + hdb * 16 + r] = (h16)(a1 * inv1[j]);
      }
  }
}

// ---------------- launch ----------------
extern "C" void kernel_launch(void* const* d_in, const int* in_sizes, int n_in,
                              void* d_out, int out_size, void* d_ws, size_t ws_size,
                              hipStream_t stream) {
  char* ws = (char*)d_ws;
  h16* xb  = (h16*)(ws + 0);                   // 8 MiB X f16
  h16* qb  = (h16*)(ws + 8388608);             // 8 MiB Q (pre-scaled by 0.125*log2e)
  h16* kb  = (h16*)(ws + 16777216);            // 8 MiB K
  h16* vt  = (h16*)(ws + 25165824);            // 8 MiB V^T (pi-permuted cols)
  h16* ctx = (h16*)(ws + 33554432);            // 8 MiB attention output
  h16* wqb = (h16*)(ws + 41943040);            // 512 KiB each
  h16* wkb = (h16*)(ws + 41943040 + 524288);
  h16* wvb = (h16*)(ws + 41943040 + 2 * 524288);
  h16* wob = (h16*)(ws + 41943040 + 3 * 524288);
  float* bof = (float*)(ws + 41943040 + 4 * 524288);

  conv_all<<<20482, 256, 0, stream>>>(d_in[0], d_in[1], d_in[2], d_in[3], d_in[4],
                                      d_in[5], xb, wqb, wkb, wvb, wob, bof);
  gemm_qkv<<<dim3(M_ / 128, D_ / 128, 3), 256, 0, stream>>>(xb, wqb, wkb, wvb, qb, kb, vt);
  attn_kernel<<<dim3(H_, 64, B_), 256, 0, stream>>>(qb, kb, vt, ctx);
  gemm_out<<<dim3(M_ / 128, D_ / 128, 1), 256, 0, stream>>>(ctx, wob, bof, d_out, d_in[0]);
}

// Round 8
// 169.699 us; speedup vs baseline: 1.4807x; 1.0594x over previous
//
#include <hip/hip_runtime.h>

#define B_  2
#define T_  4096
#define D_  512
#define H_  8
#define HD_ 64
#define M_  (B_*T_)   // 8192 rows

typedef _Float16 h16;
typedef _Float16 v8h __attribute__((ext_vector_type(8)));
typedef _Float16 h2  __attribute__((ext_vector_type(2)));
typedef float v4f __attribute__((ext_vector_type(4)));
typedef unsigned short us;
typedef unsigned short us8 __attribute__((ext_vector_type(8)));

union PaU { v8h v; h2 p[4]; };

#define AS1 __attribute__((address_space(1)))
#define AS3 __attribute__((address_space(3)))

__device__ __forceinline__ float bf2f(us u){
  union { unsigned int i; float f; } v; v.i = ((unsigned int)u) << 16; return v.f;
}
__device__ __forceinline__ us f2bf(float f){
  union { float f; unsigned int u; } v; v.f = f;
  unsigned int r = v.u + 0x7FFFu + ((v.u >> 16) & 1u);
  return (us)(r >> 16);
}
__device__ __forceinline__ v4f zero4(){ v4f z; z[0]=0.f; z[1]=0.f; z[2]=0.f; z[3]=0.f; return z; }

__device__ __forceinline__ void glds16(const h16* g, h16* l){
  __builtin_amdgcn_global_load_lds((const AS1 int*)(const void*)g,
                                   (AS3 int*)(void*)l, 16, 0, 0);
}

__device__ __forceinline__ h2 pkrtz(float a, float b){
  auto t = __builtin_amdgcn_cvt_pkrtz(a, b);   // v_cvt_pkrtz_f16_f32: {f16(a),f16(b)}
  h2 r; __builtin_memcpy(&r, &t, sizeof(r)); return r;
}

#define MFMA32 __builtin_amdgcn_mfma_f32_16x16x32_f16

// ---------------- fused convert, ROUND 16: vectorized 8 elems/thread ------------------
// X: 2048 blocks; W: 4x128; bias: 1 block (64 threads). Probe semantics unchanged:
// 256 u16 samples from the block's region trip the bf16-decode magnitude test iff f32.
__global__ __launch_bounds__(256) void conv_all(
    const void* __restrict__ x, const void* __restrict__ w0, const void* __restrict__ w1,
    const void* __restrict__ w2, const void* __restrict__ w3, const void* __restrict__ bo,
    h16* __restrict__ xb, h16* __restrict__ d0, h16* __restrict__ d1,
    h16* __restrict__ d2, h16* __restrict__ d3, float* __restrict__ bof)
{
  const int bid = blockIdx.x, tid = threadIdx.x;
  const void* src; int e0; int seg;
  h16* dst = nullptr;
  if (bid < 2048)      { src = x; e0 = bid * 2048; dst = xb; seg = 0; }
  else if (bid < 2560) {
    const int wsel = (bid - 2048) >> 7;
    src = (wsel == 0) ? w0 : (wsel == 1) ? w1 : (wsel == 2) ? w2 : w3;
    dst = (wsel == 0) ? d0 : (wsel == 1) ? d1 : (wsel == 2) ? d2 : d3;
    e0 = ((bid - 2048) & 127) * 2048; seg = 0;
  } else                { src = bo; e0 = 0; seg = 1; }

  __shared__ int sflag;
  if (tid == 0) sflag = 0;
  __syncthreads();
  const float probe = bf2f(((const us*)src)[e0 + tid]);
  if (!(fabsf(probe) < 1e4f)) atomicAdd(&sflag, 1);
  __syncthreads();
  const int isf32 = (sflag != 0);

  if (seg) {                                   // bias: 512 f32 out
    if (tid < 64) {
      const int i = tid * 8;
#pragma unroll
      for (int e = 0; e < 8; e++)
        bof[i + e] = isf32 ? ((const float*)src)[i + e] : bf2f(((const us*)src)[i + e]);
    }
    return;
  }
  const int i = e0 + tid * 8;
  float v[8];
  if (isf32) {
    const float* pf = (const float*)src + i;
    const float4 a = *(const float4*)pf;
    const float4 c = *(const float4*)(pf + 4);
    v[0]=a.x; v[1]=a.y; v[2]=a.z; v[3]=a.w; v[4]=c.x; v[5]=c.y; v[6]=c.z; v[7]=c.w;
  } else {
    const us8 u = *(const us8*)((const us*)src + i);
#pragma unroll
    for (int e = 0; e < 8; e++) v[e] = bf2f(u[e]);
  }
  v8h o;
#pragma unroll
  for (int e = 0; e < 8; e++) o[e] = (h16)v[e];
  *(v8h*)(dst + i) = o;
}

// ---------------- GEMM core: Y[M,512] = A[M,512]*W[512,512]^T, f16 MFMA, fp32 acc -----
__device__ __forceinline__ void stage4(const h16* __restrict__ A, const h16* __restrict__ W,
                                       int m0, int n0, int kk, h16* sA, h16* sB, int tid){
  const int colA = (tid & 3) << 3;
  const int rowT = tid >> 2;
#pragma unroll
  for (int rd = 0; rd < 2; rd++) {
    const int row = rd * 64 + rowT;
    const int f = rd * 2048 + tid * 8;
    glds16(A + (size_t)(m0 + row) * D_ + kk + colA, sA + f);
    glds16(W + (size_t)(n0 + row) * D_ + kk + colA, sB + f);
  }
}

__device__ __forceinline__ void gemm_core(const h16* __restrict__ A,
                                          const h16* __restrict__ W,
                                          int m0, int n0, h16* sA, h16* sB,
                                          v4f acc[4][4]) {
  const int tid = threadIdx.x;
  const int lane = tid & 63, wid = tid >> 6;
  const int r = lane & 15, q = lane >> 4;
#pragma unroll
  for (int i = 0; i < 4; i++)
#pragma unroll
    for (int j = 0; j < 4; j++) acc[i][j] = zero4();

  stage4(A, W, m0, n0, 0, sA, sB, tid);
#pragma unroll 1
  for (int kt = 0; kt < 16; kt++) {
    if (kt < 15) {
      const int nb = (kt + 1) & 1;
      stage4(A, W, m0, n0, (kt + 1) * 32, sA + nb * 4096, sB + nb * 4096, tid);
      asm volatile("s_waitcnt vmcnt(4)" ::: "memory");   // current tile's 4 landed
    } else {
      asm volatile("s_waitcnt vmcnt(0)" ::: "memory");
    }
    asm volatile("s_barrier" ::: "memory");
    const h16* pA = sA + (kt & 1) * 4096 + ((wid & 1) * 64 + r) * 32 + q * 8;
    const h16* pB = sB + (kt & 1) * 4096 + ((wid >> 1) * 64 + r) * 32 + q * 8;
    v8h a[4], b[4];
#pragma unroll
    for (int i = 0; i < 4; i++) a[i] = *(const v8h*)(pA + i * 512);
#pragma unroll
    for (int j = 0; j < 4; j++) b[j] = *(const v8h*)(pB + j * 512);
#pragma unroll
    for (int i = 0; i < 4; i++)
#pragma unroll
      for (int j = 0; j < 4; j++)
        acc[i][j] = MFMA32(a[i], b[j], acc[i][j], 0, 0, 0);
    asm volatile("s_barrier" ::: "memory");              // done reading cur buffers
  }
}

// z=0 -> Q (pre-scaled by 0.125*log2e for exp2 softmax); z=1 -> K
// z=2 -> VT[b,h,hd,t'] with t' = pi-permuted within each 64-wide t-tile (PV slot order
// pi(8q+j)=4q+(j&3)+16*(j>>2), applied per 32-half) — attn PV B reads v8h linearly.
__global__ __launch_bounds__(256, 3) void gemm_qkv(
    const h16* __restrict__ X,
    const h16* __restrict__ Wq, const h16* __restrict__ Wk, const h16* __restrict__ Wv,
    h16* __restrict__ Qo, h16* __restrict__ Ko, h16* __restrict__ VTo)
{
  __shared__ h16 sA[2 * 4096], sB[2 * 4096];
  const h16* W = (blockIdx.z == 0) ? Wq : (blockIdx.z == 1 ? Wk : Wv);
  const int m0 = blockIdx.x * 128, n0 = blockIdx.y * 128;
  v4f acc[4][4];
  gemm_core(X, W, m0, n0, sA, sB, acc);
  const int lane = threadIdx.x & 63, wid = threadIdx.x >> 6;
  const int r = lane & 15, q = lane >> 4;
  const int wm = m0 + (wid & 1) * 64, wn = n0 + (wid >> 1) * 64;
  if (blockIdx.z == 2) {
#pragma unroll
    for (int i = 0; i < 4; i++)
#pragma unroll
      for (int j = 0; j < 4; j++)
#pragma unroll
        for (int rr = 0; rr < 4; rr++) {
          const int row = wm + i*16 + q*4 + rr;   // b*T + t
          const int col = wn + j*16 + r;          // h*64 + hd
          const int bb = row >> 12, tt = row & (T_ - 1);
          const int hh = col >> 6,  hd = col & 63;
          const int t6 = tt & 63;
          const int tperm = (tt & ~63) | (t6 & 3) | (((t6 >> 2) & 3) << 3)
                          | (((t6 >> 4) & 1) << 2) | (t6 & 32);
          VTo[((size_t)(((bb << 3) + hh) << 6) + hd) * T_ + tperm] = (h16)acc[i][j][rr];
        }
  } else {
    h16* Y = (blockIdx.z == 0) ? Qo : Ko;
    const float sc = (blockIdx.z == 0) ? 0.1803368801f : 1.0f;  // 1/8 * log2(e)
#pragma unroll
    for (int i = 0; i < 4; i++)
#pragma unroll
      for (int j = 0; j < 4; j++)
#pragma unroll
        for (int rr = 0; rr < 4; rr++)
          Y[(size_t)(wm + i*16 + q*4 + rr) * D_ + wn + j*16 + r] = (h16)(acc[i][j][rr] * sc);
  }
}

__global__ __launch_bounds__(256, 3) void gemm_out(
    const h16* __restrict__ A, const h16* __restrict__ W,
    const float* __restrict__ bias, void* __restrict__ out, const void* __restrict__ xprobe)
{
  __shared__ h16 sA[2 * 4096], sB[2 * 4096];
  __shared__ int sflag;
  if (threadIdx.x == 0) sflag = 0;
  __syncthreads();
  const float probe = bf2f(((const us*)xprobe)[threadIdx.x]);
  if (!(fabsf(probe) < 1e4f)) atomicAdd(&sflag, 1);
  __syncthreads();
  const int flag = (sflag != 0);

  const int m0 = blockIdx.x * 128, n0 = blockIdx.y * 128;
  v4f acc[4][4];
  gemm_core(A, W, m0, n0, sA, sB, acc);
  const int lane = threadIdx.x & 63, wid = threadIdx.x >> 6;
  const int r = lane & 15, q = lane >> 4;
  const int wm = m0 + (wid & 1) * 64, wn = n0 + (wid >> 1) * 64;
#pragma unroll
  for (int i = 0; i < 4; i++)
#pragma unroll
    for (int j = 0; j < 4; j++)
#pragma unroll
      for (int rr = 0; rr < 4; rr++) {
        const int row = wm + i*16 + q*4 + rr;
        const int col = wn + j*16 + r;
        const float v = acc[i][j][rr] + bias[col];
        if (flag) ((float*)out)[(size_t)row * D_ + col] = v;
        else ((us*)out)[(size_t)row * D_ + col] = f2bf(v);
      }
}

// ---------------- flash attention, ROUND 16: 1-barrier pipeline + setprio ------------
// Round-15c structure (2D wave split kw x qw, glds16 double-buffer) with the schedule
// tightened: ONE barrier per tile. stage(t+1) is issued AFTER the barrier into the
// buffer whose readers provably finished (they completed compute(t-1) before arriving
// at barrier(t)); its latency lands under compute(t). vmcnt(0) before the barrier
// drains this wave's stage(t) so after the barrier all LDS writes are visible.
// s_setprio(1) wraps the MFMA clusters (T5 — helps when co-resident blocks are at
// different phases). The masked diagonal tile is peeled so the hot loop is branch-free.
__global__ __launch_bounds__(256, 4) void attn_kernel(
    const h16* __restrict__ Q, const h16* __restrict__ K,
    const h16* __restrict__ VT, h16* __restrict__ Ctx)
{
  const int h = blockIdx.x;
  const int pos = blockIdx.y + (blockIdx.z << 6);      // dispatch position 0..127
  const int qc = 63 - (pos >> 1);                      // strict LPT: heavy first
  const int b  = pos & 1;
  const int tid = threadIdx.x;
  const int wid = tid >> 6, lane = tid & 63;
  const int r = lane & 15, quad = lane >> 4;
  const int kw = wid & 1, qw = wid >> 1;

  const size_t headoff = (size_t)b * T_ * D_ + (size_t)h * HD_;
  const h16* Qh  = Q + headoff;
  const h16* Kh  = K + headoff;
  const h16* VTh = VT + (size_t)(b * H_ + h) * HD_ * T_;
  h16* Ch = Ctx + headoff;

  __shared__ h16 smem[4][4096];    // [0],[1]=K dbuf; [2],[3]=V dbuf; epilogue aliases

  const int q0 = qc * 64 + qw * 32;
  const int ntiles = qc + 1;

  // Q fragments (B-operand of swapped QK^T): 2 q-subtiles x 2 hd-halves
  const v8h aq00 = *(const v8h*)(Qh + (size_t)(q0 + r) * D_ + quad * 8);
  const v8h aq01 = *(const v8h*)(Qh + (size_t)(q0 + r) * D_ + 32 + quad * 8);
  const v8h aq10 = *(const v8h*)(Qh + (size_t)(q0 + 16 + r) * D_ + quad * 8);
  const v8h aq11 = *(const v8h*)(Qh + (size_t)(q0 + 16 + r) * D_ + 32 + quad * 8);

  v8h vone;
#pragma unroll
  for (int e = 0; e < 8; e++) vone[e] = (h16)1;

  v4f o0[4], o1[4];
#pragma unroll
  for (int j = 0; j < 4; j++) { o0[j] = zero4(); o1[j] = zero4(); }
  v4f ld0 = zero4(), ld1 = zero4();

  // staging: running pointers, XOR-swizzled dest rows
  const int srow = tid >> 3;                           // 0..31
  const int sj = (tid & 7) ^ (srow & 7);
  const h16* kcur = Kh + (size_t)srow * D_ + sj * 8;
  const h16* vcur = VTh + (size_t)srow * T_ + sj * 8;

  glds16(kcur, &smem[0][tid * 8]); glds16(kcur + 32 * D_, &smem[0][2048 + tid * 8]);
  glds16(vcur, &smem[2][tid * 8]); glds16(vcur + 32 * T_, &smem[2][2048 + tid * 8]);
  kcur += 64 * D_; vcur += 64;

  // hoisted lane constants
  const int xo0 = (quad ^ (r & 7)) * 8;                // K hd-half 0
  const int xo1 = ((quad + 4) ^ (r & 7)) * 8;          // K hd-half 1
  const int xov = ((quad + kw * 4) ^ (r & 7)) * 8;     // V cols kw*32 + quad*8
  const int krow = kw * 32 + r;                        // this wave's K LDS row base
  const int kloc = kw * 32 + quad * 4;                 // k offset of s-reg rr=0
  const int qlim0 = qw * 32 + r, qlim1 = qw * 32 + 16 + r;

#define ATT_TILE(CB, MASKED) do {                                              \
    const h16* sKc = smem[(CB)];                                               \
    const h16* sVc = smem[2 + (CB)];                                           \
    const h16* bK = sKc + krow * 64;                                           \
    const v8h ka0 = *(const v8h*)(bK + xo0);                                   \
    const v8h ka1 = *(const v8h*)(bK + xo1);                                   \
    const v8h ka2 = *(const v8h*)(bK + 16 * 64 + xo0);                         \
    const v8h ka3 = *(const v8h*)(bK + 16 * 64 + xo1);                         \
    v8h va[4];                                                                 \
    _Pragma("unroll")                                                          \
    for (int j = 0; j < 4; j++)                                                \
      va[j] = *(const v8h*)(sVc + (j * 16 + r) * 64 + xov);                    \
    v4f s00 = zero4(), s10 = zero4(), s01 = zero4(), s11 = zero4();            \
    __builtin_amdgcn_s_setprio(1);                                             \
    s00 = MFMA32(ka0, aq00, s00, 0,0,0); s00 = MFMA32(ka1, aq01, s00, 0,0,0);  \
    s10 = MFMA32(ka2, aq00, s10, 0,0,0); s10 = MFMA32(ka3, aq01, s10, 0,0,0);  \
    s01 = MFMA32(ka0, aq10, s01, 0,0,0); s01 = MFMA32(ka1, aq11, s01, 0,0,0);  \
    s11 = MFMA32(ka2, aq10, s11, 0,0,0); s11 = MFMA32(ka3, aq11, s11, 0,0,0);  \
    __builtin_amdgcn_s_setprio(0);                                             \
    PaU pa0, pa1;                                                              \
    _Pragma("unroll")                                                          \
    for (int qb = 0; qb < 2; qb++) {                                           \
      const v4f& sa = qb ? s01 : s00;                                          \
      const v4f& sb = qb ? s11 : s10;                                          \
      const int qlim = qb ? qlim1 : qlim0;                                     \
      float e0[4], e1[4];                                                      \
      _Pragma("unroll")                                                        \
      for (int rr = 0; rr < 4; rr++) {                                         \
        float v0 = sa[rr], v1 = sb[rr];                                        \
        if (MASKED) {                                                          \
          if (kloc + rr > qlim)      v0 = -1e30f;                              \
          if (kloc + 16 + rr > qlim) v1 = -1e30f;                              \
        }                                                                      \
        e0[rr] = exp2f(v0); e1[rr] = exp2f(v1);                                \
      }                                                                        \
      PaU* pa = qb ? &pa1 : &pa0;                                              \
      pa->p[0] = pkrtz(e0[0], e0[1]); pa->p[1] = pkrtz(e0[2], e0[3]);          \
      pa->p[2] = pkrtz(e1[0], e1[1]); pa->p[3] = pkrtz(e1[2], e1[3]);          \
    }                                                                          \
    __builtin_amdgcn_s_setprio(1);                                             \
    ld0 = MFMA32(pa0.v, vone, ld0, 0,0,0);                                     \
    ld1 = MFMA32(pa1.v, vone, ld1, 0,0,0);                                     \
    _Pragma("unroll")                                                          \
    for (int j = 0; j < 4; j++) {                                              \
      o0[j] = MFMA32(pa0.v, va[j], o0[j], 0,0,0);                              \
      o1[j] = MFMA32(pa1.v, va[j], o1[j], 0,0,0);                              \
    }                                                                          \
    __builtin_amdgcn_s_setprio(0);                                             \
  } while(0)

#pragma unroll 1
  for (int kt = 0; kt < ntiles - 1; kt++) {
    asm volatile("s_waitcnt vmcnt(0)" ::: "memory");   // my stage(kt) landed
    asm volatile("s_barrier" ::: "memory");            // all stage(kt) visible; bufs free
    const int nb = (kt + 1) & 1;
    glds16(kcur, &smem[nb][tid * 8]);
    glds16(kcur + 32 * D_, &smem[nb][2048 + tid * 8]);
    glds16(vcur, &smem[2 + nb][tid * 8]);
    glds16(vcur + 32 * T_, &smem[2 + nb][2048 + tid * 8]);
    kcur += 64 * D_; vcur += 64;
    ATT_TILE(kt & 1, false);
  }
  // peeled diagonal tile
  asm volatile("s_waitcnt vmcnt(0)" ::: "memory");
  asm volatile("s_barrier" ::: "memory");
  ATT_TILE((ntiles - 1) & 1, true);
#undef ATT_TILE

  // ---------------- epilogue: cross-kw reduction (aliases dead K/V buffers) ----------
  __syncthreads();                   // all waves done with LDS tiles
  float* const red = (float*)&smem[0][0];      // 4288 f32 = 17152 B
  float* const seg = red + qw * 2112;          // 32 rows x 66
  float* const lred = red + 4224;
  if (kw) {
#pragma unroll
    for (int hdb = 0; hdb < 4; hdb++)
#pragma unroll
      for (int j = 0; j < 4; j++) {
        seg[(quad * 4 + j) * 66 + hdb * 16 + r] = o0[hdb][j];
        seg[(16 + quad * 4 + j) * 66 + hdb * 16 + r] = o1[hdb][j];
      }
    if (r == 0) {
#pragma unroll
      for (int j = 0; j < 4; j++) {
        lred[qw * 32 + quad * 4 + j] = ld0[j];
        lred[qw * 32 + 16 + quad * 4 + j] = ld1[j];
      }
    }
  }
  __syncthreads();
  if (!kw) {
    float inv0[4], inv1[4];
#pragma unroll
    for (int j = 0; j < 4; j++) {
      inv0[j] = 1.0f / (ld0[j] + lred[qw * 32 + quad * 4 + j]);
      inv1[j] = 1.0f / (ld1[j] + lred[qw * 32 + 16 + quad * 4 + j]);
    }
#pragma unroll
    for (int hdb = 0; hdb < 4; hdb++)
#pragma unroll
      for (int j = 0; j < 4; j++) {
        const float a0 = o0[hdb][j] + seg[(quad * 4 + j) * 66 + hdb * 16 + r];
        const float a1 = o1[hdb][j] + seg[(16 + quad * 4 + j) * 66 + hdb * 16 + r];
        Ch[(size_t)(q0 + quad * 4 + j) * D_ + hdb * 16 + r] = (h16)(a0 * inv0[j]);
        Ch[(size_t)(q0 + 16 + quad * 4 + j) * D_ + hdb * 16 + r] = (h16)(a1 * inv1[j]);
      }
  }
}

// ---------------- launch ----------------
extern "C" void kernel_launch(void* const* d_in, const int* in_sizes, int n_in,
                              void* d_out, int out_size, void* d_ws, size_t ws_size,
                              hipStream_t stream) {
  char* ws = (char*)d_ws;
  h16* xb  = (h16*)(ws + 0);                   // 8 MiB X f16
  h16* qb  = (h16*)(ws + 8388608);             // 8 MiB Q (pre-scaled by 0.125*log2e)
  h16* kb  = (h16*)(ws + 16777216);            // 8 MiB K
  h16* vt  = (h16*)(ws + 25165824);            // 8 MiB V^T (pi-permuted cols)
  h16* ctx = (h16*)(ws + 33554432);            // 8 MiB attention output
  h16* wqb = (h16*)(ws + 41943040);            // 512 KiB each
  h16* wkb = (h16*)(ws + 41943040 + 524288);
  h16* wvb = (h16*)(ws + 41943040 + 2 * 524288);
  h16* wob = (h16*)(ws + 41943040 + 3 * 524288);
  float* bof = (float*)(ws + 41943040 + 4 * 524288);

  conv_all<<<2561, 256, 0, stream>>>(d_in[0], d_in[1], d_in[2], d_in[3], d_in[4],
                                     d_in[5], xb, wqb, wkb, wvb, wob, bof);
  gemm_qkv<<<dim3(M_ / 128, D_ / 128, 3), 256, 0, stream>>>(xb, wqb, wkb, wvb, qb, kb, vt);
  attn_kernel<<<dim3(H_, 64, B_), 256, 0, stream>>>(qb, kb, vt, ctx);
  gemm_out<<<dim3(M_ / 128, D_ / 128, 1), 256, 0, stream>>>(ctx, wob, bof, d_out, d_in[0]);
}